// Round 7
// baseline (415.556 us; speedup 1.0000x reference)
//
#include <hip/hip_runtime.h>
#include <hip/hip_bf16.h>

// TokenRoutedMLP: N=32768 tokens, H=1024, 8 routed experts (id%8) + shared expert.
// Grouped bf16 MFMA GEMMs; shared expert folded via concat weights; gate/up
// interleaved by 16 cols in W1 so silu pairing is in-register.
// GEMM structure (T2+T3+T4+T5): 256x256 tile, BK=32, 8 waves, ring-4 LDS
// (128 KiB), counted s_waitcnt vmcnt(12) + raw s_barrier (loads span 3 MFMA
// phases), fragment-ordered LDS via pre-permuted global source (conflict-free
// ds_read_b128: addr = frag*1024B + lane*16B), setprio around MFMA cluster.
// global_load_lds: LDS dest wave-uniform base + lane*16B (m104/m108).

#define N_TOK 32768
#define HD 1024
#define NE 8

typedef __attribute__((ext_vector_type(8))) short bf16x8;
typedef __attribute__((ext_vector_type(8))) unsigned short u16x8;
typedef __attribute__((ext_vector_type(4))) float f32x4;

__device__ __forceinline__ unsigned short f2bf(float f) {
  unsigned int x = __float_as_uint(f);
  x += 0x7fffu + ((x >> 16) & 1u);   // RTNE
  return (unsigned short)(x >> 16);
}

__device__ __forceinline__ void gld16(const unsigned short* g, unsigned short* l) {
  __builtin_amdgcn_global_load_lds(
      (const __attribute__((address_space(1))) unsigned int*)g,
      (__attribute__((address_space(3))) unsigned int*)l,
      16, 0, 0);
}

__device__ __forceinline__ int expert_of(int id) {
  int v = id < 0 ? 0 : (id > 99999 ? 99999 : id);
  return v & 7;
}

// ---------------- routing (LDS-histogram; 8 global atomics per block) ----------
__global__ void k_zero(int* ctrl) {
  if (threadIdx.x < 16) ctrl[threadIdx.x] = 0;   // cnt[8], cursor[8]
}

__global__ void k_count(const int* __restrict__ ids, int* __restrict__ cnt) {
  __shared__ int l[NE];
  if (threadIdx.x < NE) l[threadIdx.x] = 0;
  __syncthreads();
  int t = blockIdx.x * 256 + threadIdx.x;
  atomicAdd(&l[expert_of(ids[t])], 1);
  __syncthreads();
  if (threadIdx.x < NE) atomicAdd(&cnt[threadIdx.x], l[threadIdx.x]);
}

__global__ void k_scan(const int* __restrict__ cnt, int* __restrict__ off) {
  if (threadIdx.x == 0 && blockIdx.x == 0) {
    int a = 0;
    for (int e = 0; e < NE; e++) { off[e] = a; a += (cnt[e] + 127) & ~127; }
    off[NE] = a;
  }
}

__global__ void k_fill(const int* __restrict__ ids, int* __restrict__ cursor,
                       const int* __restrict__ off, int* __restrict__ perm) {
  __shared__ int lcnt[NE], lbase[NE];
  if (threadIdx.x < NE) lcnt[threadIdx.x] = 0;
  __syncthreads();
  int t = blockIdx.x * 256 + threadIdx.x;
  int e = expert_of(ids[t]);
  int r = atomicAdd(&lcnt[e], 1);          // rank within block
  __syncthreads();
  if (threadIdx.x < NE)
    lbase[threadIdx.x] = atomicAdd(&cursor[threadIdx.x], lcnt[threadIdx.x]);
  __syncthreads();
  perm[off[e] + lbase[e] + r] = t;
}

// ---------------- conversions / weight build ----------------
__global__ void k_cvt_x(const float* __restrict__ src, unsigned short* __restrict__ dst) {
  size_t i = ((size_t)blockIdx.x * 256 + threadIdx.x) * 8;
  float4 a = *reinterpret_cast<const float4*>(src + i);
  float4 b = *reinterpret_cast<const float4*>(src + i + 4);
  u16x8 o;
  o[0]=f2bf(a.x); o[1]=f2bf(a.y); o[2]=f2bf(a.z); o[3]=f2bf(a.w);
  o[4]=f2bf(b.x); o[5]=f2bf(b.y); o[6]=f2bf(b.z); o[7]=f2bf(b.w);
  *reinterpret_cast<u16x8*>(dst + i) = o;
}

// row remap: mode 0 plain; mode 1 gate-interleave; mode 2 up-interleave
__device__ __forceinline__ int rowmap(int c, int mode) {
  if (mode == 0) return c;
  return ((c >> 4) << 5) + (c & 15) + (mode == 2 ? 16 : 0);
}

// transpose-convert: src f32 [R][C] per expert -> dst bf16 [rowmap(col)][src_row], stride HD
__global__ void k_transpose_cvt(const float* __restrict__ src0, unsigned short* __restrict__ dst0,
                                int C, int mode, size_t src_estride, size_t dst_estride) {
  const float* src = src0 + blockIdx.z * src_estride;
  unsigned short* dst = dst0 + blockIdx.z * dst_estride;
  __shared__ __attribute__((aligned(16))) float tile[32][33];
  int t = threadIdx.x;
  int r0 = blockIdx.y * 32, c0 = blockIdx.x * 32;
  int row = t >> 3, c4 = (t & 7) * 4;
  float4 v = *reinterpret_cast<const float4*>(src + (size_t)(r0 + row) * C + c0 + c4);
  tile[row][c4+0] = v.x; tile[row][c4+1] = v.y; tile[row][c4+2] = v.z; tile[row][c4+3] = v.w;
  __syncthreads();
  ushort4 o;
  o.x = f2bf(tile[c4+0][row]); o.y = f2bf(tile[c4+1][row]);
  o.z = f2bf(tile[c4+2][row]); o.w = f2bf(tile[c4+3][row]);
  int orow = rowmap(c0 + row, mode);
  *reinterpret_cast<ushort4*>(dst + (size_t)orow * HD + r0 + c4) = o;
}

// copy-convert: src f32 [rows][cols] -> dst row (1024+rowmap(r) if mode, else r), col dcol+c
__global__ void k_copy_cvt(const float* __restrict__ src, unsigned short* __restrict__ dst,
                           int cols, int mode, int dcol, size_t dst_estride) {
  size_t i = ((size_t)blockIdx.x * 256 + threadIdx.x) * 4;
  int r = (int)(i / cols), c = (int)(i % cols);
  int row = (mode == 0) ? r : (1024 + rowmap(r, mode));
  float4 v = *reinterpret_cast<const float4*>(src + i);
  ushort4 o; o.x=f2bf(v.x); o.y=f2bf(v.y); o.z=f2bf(v.z); o.w=f2bf(v.w);
  *reinterpret_cast<ushort4*>(dst + blockIdx.z * dst_estride
                              + (size_t)row * HD + dcol + c) = o;
}

// ---------------- GEMM 1: x @ W1(interleaved gate/up) + silu*mul -> inter ----------
// 512 thr = 8 waves (2M x 4N). Tile M=256 tokens, N=256 W1-rows, BK=32, NT=32.
// LDS slot s=(row>>4)*64 + kblk*16 + (row&15); thread tid stages slots {tid, tid+512}
// so ds_read frag = base + (rowblk)*1024B + lane*16B (conflict-free).
__global__ __launch_bounds__(512, 2) void k_gu(
    const unsigned short* __restrict__ xbf,
    const unsigned short* __restrict__ W1,   // [8][2048][1024]
    const int* __restrict__ perm, const int* __restrict__ cnt, const int* __restrict__ off,
    unsigned short* __restrict__ inter) {
  const int e = blockIdx.z;
  const int ce = cnt[e];
  const int m0 = blockIdx.y * 256;
  if (m0 >= ce) return;
  const int cep = (ce + 127) & ~127;
  const int n0 = blockIdx.x * 256;
  const int oe = off[e];
  __shared__ __attribute__((aligned(16))) unsigned short sm[65536];  // A: 4x16KB, B: 4x16KB
  const int tid = threadIdx.x;
  const int lane = tid & 63;
  const int wv = tid >> 6;
  const int wm = wv >> 2, wn = wv & 3;

  // slot -> (row, kblk) for this thread's two slots (s = tid, tid+512)
  const int r0s = ((tid >> 6) << 4) | (tid & 15);         // rows 0..127
  const int r1s = r0s + 128;                               // rows 128..255
  const int kb = ((tid >> 4) & 3) * 8;                     // k element offset
  int ia = m0 + r0s; if (ia > ce - 1) ia = ce - 1;
  int ib = m0 + r1s; if (ib > ce - 1) ib = ce - 1;
  const unsigned short* gA0 = xbf + (size_t)perm[oe + ia] * HD + kb;
  const unsigned short* gA1 = xbf + (size_t)perm[oe + ib] * HD + kb;
  const unsigned short* gB0 = W1 + ((size_t)e << 21) + (size_t)(n0 + r0s) * HD + kb;
  const unsigned short* gB1 = W1 + ((size_t)e << 21) + (size_t)(n0 + r1s) * HD + kb;

  f32x4 acc[8][4];
#pragma unroll
  for (int mi = 0; mi < 8; mi++)
#pragma unroll
    for (int ni = 0; ni < 4; ni++) acc[mi][ni] = (f32x4){0.f, 0.f, 0.f, 0.f};

  auto STAGE = [&](int b, int kt) {
    const int ko = kt * 32;
    unsigned short* la = sm + b * 8192 + wv * 512;          // wave-uniform dests
    unsigned short* lb = sm + 32768 + b * 8192 + wv * 512;
    gld16(gA0 + ko, la);
    gld16(gA1 + ko, la + 4096);
    gld16(gB0 + ko, lb);
    gld16(gB1 + ko, lb + 4096);
  };
  auto COMPUTE = [&](int b) {
    const unsigned short* A = sm + b * 8192;
    const unsigned short* B = sm + 32768 + b * 8192;
    bf16x8 a[8], bb[4];
#pragma unroll
    for (int mi = 0; mi < 8; mi++)
      a[mi] = *reinterpret_cast<const bf16x8*>(A + (wm * 8 + mi) * 512 + lane * 8);
#pragma unroll
    for (int ni = 0; ni < 4; ni++)
      bb[ni] = *reinterpret_cast<const bf16x8*>(B + (wn * 4 + ni) * 512 + lane * 8);
    __builtin_amdgcn_s_setprio(1);
#pragma unroll
    for (int mi = 0; mi < 8; mi++)
#pragma unroll
      for (int ni = 0; ni < 4; ni++)
        acc[mi][ni] = __builtin_amdgcn_mfma_f32_16x16x32_bf16(a[mi], bb[ni], acc[mi][ni], 0, 0, 0);
    __builtin_amdgcn_s_setprio(0);
  };

  STAGE(0, 0); STAGE(1, 1); STAGE(2, 2);
#pragma unroll 1
  for (int kt = 0; kt < 29; kt++) {
    STAGE((kt + 3) & 3, kt + 3);
    asm volatile("s_waitcnt vmcnt(12)\n\ts_barrier" ::: "memory");  // tile kt ready
    COMPUTE(kt & 3);
    asm volatile("s_barrier" ::: "memory");                          // reads done
  }
  asm volatile("s_waitcnt vmcnt(8)\n\ts_barrier" ::: "memory");
  COMPUTE(1);
  asm volatile("s_barrier" ::: "memory");
  asm volatile("s_waitcnt vmcnt(4)\n\ts_barrier" ::: "memory");
  COMPUTE(2);
  asm volatile("s_barrier" ::: "memory");
  asm volatile("s_waitcnt vmcnt(0)\n\ts_barrier" ::: "memory");
  COMPUTE(3);

  // epilogue: n-frags alternate (gate, up) per 16; pair in-register.
  const int colbase = (n0 + wn * 64) >> 1;
#pragma unroll
  for (int mi = 0; mi < 8; mi++)
#pragma unroll
    for (int p = 0; p < 2; p++)
#pragma unroll
      for (int r = 0; r < 4; r++) {
        int m = wm * 128 + mi * 16 + (lane >> 4) * 4 + r;
        if (m0 + m < cep) {
          float g = acc[mi][2 * p][r];
          float u = acc[mi][2 * p + 1][r];
          float sv = g / (1.f + __expf(-g)) * u;
          inter[(size_t)(oe + m0 + m) * HD + colbase + p * 16 + (lane & 15)] = f2bf(sv);
        }
      }
}

// ---------------- GEMM 2: inter @ Dcat -> out (scatter rows via perm) ----------------
// Same pipeline. Tile M=256, N=256 out cols, BK=32, NT=32.
__global__ __launch_bounds__(512, 2) void k_down(
    const unsigned short* __restrict__ inter,
    const unsigned short* __restrict__ Dt,   // [8][1024][1024] B^T
    const int* __restrict__ perm, const int* __restrict__ cnt, const int* __restrict__ off,
    float* __restrict__ out) {
  const int e = blockIdx.z;
  const int ce = cnt[e];
  const int m0 = blockIdx.y * 256;
  if (m0 >= ce) return;
  const int cep = (ce + 127) & ~127;
  const int n0 = blockIdx.x * 256;
  const int oe = off[e];
  __shared__ __attribute__((aligned(16))) unsigned short sm[65536];
  const int tid = threadIdx.x;
  const int lane = tid & 63;
  const int wv = tid >> 6;
  const int wm = wv >> 2, wn = wv & 3;

  const int r0s = ((tid >> 6) << 4) | (tid & 15);
  const int r1s = r0s + 128;
  const int kb = ((tid >> 4) & 3) * 8;
  int ia = m0 + r0s; if (ia > cep - 1) ia = cep - 1;
  int ib = m0 + r1s; if (ib > cep - 1) ib = cep - 1;
  const unsigned short* gA0 = inter + (size_t)(oe + ia) * HD + kb;
  const unsigned short* gA1 = inter + (size_t)(oe + ib) * HD + kb;
  const unsigned short* gB0 = Dt + ((size_t)e << 20) + (size_t)(n0 + r0s) * HD + kb;
  const unsigned short* gB1 = Dt + ((size_t)e << 20) + (size_t)(n0 + r1s) * HD + kb;

  f32x4 acc[8][4];
#pragma unroll
  for (int mi = 0; mi < 8; mi++)
#pragma unroll
    for (int ni = 0; ni < 4; ni++) acc[mi][ni] = (f32x4){0.f, 0.f, 0.f, 0.f};

  auto STAGE = [&](int b, int kt) {
    const int ko = kt * 32;
    unsigned short* la = sm + b * 8192 + wv * 512;
    unsigned short* lb = sm + 32768 + b * 8192 + wv * 512;
    gld16(gA0 + ko, la);
    gld16(gA1 + ko, la + 4096);
    gld16(gB0 + ko, lb);
    gld16(gB1 + ko, lb + 4096);
  };
  auto COMPUTE = [&](int b) {
    const unsigned short* A = sm + b * 8192;
    const unsigned short* B = sm + 32768 + b * 8192;
    bf16x8 a[8], bb[4];
#pragma unroll
    for (int mi = 0; mi < 8; mi++)
      a[mi] = *reinterpret_cast<const bf16x8*>(A + (wm * 8 + mi) * 512 + lane * 8);
#pragma unroll
    for (int ni = 0; ni < 4; ni++)
      bb[ni] = *reinterpret_cast<const bf16x8*>(B + (wn * 4 + ni) * 512 + lane * 8);
    __builtin_amdgcn_s_setprio(1);
#pragma unroll
    for (int mi = 0; mi < 8; mi++)
#pragma unroll
      for (int ni = 0; ni < 4; ni++)
        acc[mi][ni] = __builtin_amdgcn_mfma_f32_16x16x32_bf16(a[mi], bb[ni], acc[mi][ni], 0, 0, 0);
    __builtin_amdgcn_s_setprio(0);
  };

  STAGE(0, 0); STAGE(1, 1); STAGE(2, 2);
#pragma unroll 1
  for (int kt = 0; kt < 29; kt++) {
    STAGE((kt + 3) & 3, kt + 3);
    asm volatile("s_waitcnt vmcnt(12)\n\ts_barrier" ::: "memory");
    COMPUTE(kt & 3);
    asm volatile("s_barrier" ::: "memory");
  }
  asm volatile("s_waitcnt vmcnt(8)\n\ts_barrier" ::: "memory");
  COMPUTE(1);
  asm volatile("s_barrier" ::: "memory");
  asm volatile("s_waitcnt vmcnt(4)\n\ts_barrier" ::: "memory");
  COMPUTE(2);
  asm volatile("s_barrier" ::: "memory");
  asm volatile("s_waitcnt vmcnt(0)\n\ts_barrier" ::: "memory");
  COMPUTE(3);

#pragma unroll
  for (int mi = 0; mi < 8; mi++)
#pragma unroll
    for (int r = 0; r < 4; r++) {
      int m = wm * 128 + mi * 16 + (lane >> 4) * 4 + r;
      int gm = m0 + m;
      if (gm < ce) {                      // only real tokens scatter
        int t = perm[oe + gm];
#pragma unroll
        for (int ni = 0; ni < 4; ni++)
          out[(size_t)t * HD + n0 + wn * 64 + ni * 16 + (lane & 15)] = acc[mi][ni][r];
      }
    }
}

// ---------------- naive fp32 fallback (only if ws too small) ----------------
__global__ __launch_bounds__(256) void k_naive(
    const float* __restrict__ x, const int* __restrict__ ids,
    const float* __restrict__ gw, const float* __restrict__ uw, const float* __restrict__ dw,
    const float* __restrict__ sgw, const float* __restrict__ suw, const float* __restrict__ sdw,
    float* __restrict__ out) {
  const int t = blockIdx.x;
  const int tid = threadIdx.x;
  __shared__ float sx[1024];
  __shared__ float si[1024];
  for (int i = tid; i < 1024; i += 256) sx[i] = x[(size_t)t * 1024 + i];
  const int e = expert_of(ids[t]);
  __syncthreads();
  const float* gwe = gw + (size_t)e * 1024 * 512;
  const float* uwe = uw + (size_t)e * 1024 * 512;
  for (int j = tid; j < 512; j += 256) {
    float g = 0, u = 0, sg = 0, su = 0;
    for (int k = 0; k < 1024; k++) {
      float xv = sx[k];
      g += xv * gwe[(size_t)k * 512 + j];
      u += xv * uwe[(size_t)k * 512 + j];
      sg += xv * sgw[(size_t)j * 1024 + k];
      su += xv * suw[(size_t)j * 1024 + k];
    }
    si[j] = g / (1.f + __expf(-g)) * u;
    si[512 + j] = sg / (1.f + __expf(-sg)) * su;
  }
  __syncthreads();
  const float* dwe = dw + (size_t)e * 512 * 1024;
  for (int n = tid; n < 1024; n += 256) {
    float a = 0;
    for (int k = 0; k < 512; k++)
      a += si[k] * dwe[(size_t)k * 1024 + n] + si[512 + k] * sdw[(size_t)n * 512 + k];
    out[(size_t)t * 1024 + n] = a;
  }
}

extern "C" void kernel_launch(void* const* d_in, const int* in_sizes, int n_in,
                              void* d_out, int out_size, void* d_ws, size_t ws_size,
                              hipStream_t stream) {
  const float* x = (const float*)d_in[0];
  const int* ids = (const int*)d_in[1];          // harness passes integers as int32
  const float* gw = (const float*)d_in[2];
  const float* uw = (const float*)d_in[3];
  const float* dw = (const float*)d_in[4];
  const float* sgw = (const float*)d_in[5];
  const float* suw = (const float*)d_in[6];
  const float* sdw = (const float*)d_in[7];
  float* out = (float*)d_out;

  const size_t REQ = 186908672ull;
  if (ws_size < REQ) {
    k_naive<<<N_TOK, 256, 0, stream>>>(x, ids, gw, uw, dw, sgw, suw, sdw, out);
    return;
  }

  char* ws = (char*)d_ws;
  int* ctrl = (int*)ws;                                   // cnt[8] | cursor[8] | off[9]
  int* perm = (int*)(ws + 1024);                          // 33792 ints
  unsigned short* xbf = (unsigned short*)(ws + 262144);   // [32768][1024]
  unsigned short* W1 = (unsigned short*)(ws + 67371008ull);   // [8][2048][1024] interleaved
  unsigned short* Dt = (unsigned short*)(ws + 100925440ull);  // [8][1024][1024]
  unsigned short* inter = (unsigned short*)(ws + 117702656ull); // [33792][1024]

  k_zero<<<1, 64, 0, stream>>>(ctrl);
  k_count<<<128, 256, 0, stream>>>(ids, ctrl);
  k_scan<<<1, 64, 0, stream>>>(ctrl, ctrl + 16);
  k_fill<<<128, 256, 0, stream>>>(ids, ctrl + 8, ctrl + 16, perm);
  k_cvt_x<<<16384, 256, 0, stream>>>(x, xbf);
  // routed weights: gate/up [1024][512] -> W1 interleaved rows; down [512][1024] -> Dt plain
  k_transpose_cvt<<<dim3(16, 32, 8), 256, 0, stream>>>(gw, W1, 512, 1,
                                                       (size_t)1024 * 512, (size_t)1 << 21);
  k_transpose_cvt<<<dim3(16, 32, 8), 256, 0, stream>>>(uw, W1, 512, 2,
                                                       (size_t)1024 * 512, (size_t)1 << 21);
  k_transpose_cvt<<<dim3(32, 16, 8), 256, 0, stream>>>(dw, Dt, 1024, 0,
                                                       (size_t)512 * 1024, (size_t)1 << 20);
  // shared weights appended (replicated per expert)
  k_copy_cvt<<<dim3(512, 1, 8), 256, 0, stream>>>(sgw, W1, 1024, 1, 0, (size_t)1 << 21);
  k_copy_cvt<<<dim3(512, 1, 8), 256, 0, stream>>>(suw, W1, 1024, 2, 0, (size_t)1 << 21);
  k_copy_cvt<<<dim3(512, 1, 8), 256, 0, stream>>>(sdw, Dt, 512, 0, 512, (size_t)1 << 20);
  // grouped GEMMs (256^2 tiles, ring-4 counted-vmcnt pipeline)
  k_gu<<<dim3(8, 128, 8), 512, 0, stream>>>(xbf, W1, perm, ctrl, ctrl + 16, inter);
  k_down<<<dim3(4, 128, 8), 512, 0, stream>>>(inter, Dt, perm, ctrl, ctrl + 16, out);
}

// Round 8
// 396.223 us; speedup vs baseline: 1.0488x; 1.0488x over previous
//
#include <hip/hip_runtime.h>
#include <hip/hip_bf16.h>

// TokenRoutedMLP: N=32768 tokens, H=1024, 8 routed experts (id%8) + shared expert.
// Grouped bf16 MFMA GEMMs; shared expert folded via concat weights; gate/up
// interleaved by 16 cols in W1 so silu pairing is in-register.
// GEMM: true 8-phase schedule (T2+T3+T4+T5). 256x256 tile, BK=64, 8 waves.
// LDS 128 KiB = 2 buf x {A,B} x 2 K-half regions (16 KB each), fragment-ordered
// (conflict-free ds_read_b128, verified R7). Per phase: stage 1 half-tile
// (2 gld16) -> [vmcnt(10) even phases] -> s_barrier -> ds_read+16 MFMA -> s_barrier.
// Steady state keeps 5 half-tiles (10 loads) in flight; vmcnt(0) only at tail.
// global_load_lds: LDS dest wave-uniform base + lane*16B (m104/m108).

#define N_TOK 32768
#define HD 1024
#define NE 8

typedef __attribute__((ext_vector_type(8))) short bf16x8;
typedef __attribute__((ext_vector_type(8))) unsigned short u16x8;
typedef __attribute__((ext_vector_type(4))) float f32x4;

__device__ __forceinline__ unsigned short f2bf(float f) {
  unsigned int x = __float_as_uint(f);
  x += 0x7fffu + ((x >> 16) & 1u);   // RTNE
  return (unsigned short)(x >> 16);
}

__device__ __forceinline__ void gld16(const unsigned short* g, unsigned short* l) {
  __builtin_amdgcn_global_load_lds(
      (const __attribute__((address_space(1))) unsigned int*)g,
      (__attribute__((address_space(3))) unsigned int*)l,
      16, 0, 0);
}

__device__ __forceinline__ int expert_of(int id) {
  int v = id < 0 ? 0 : (id > 99999 ? 99999 : id);
  return v & 7;
}

// ---------------- routing (LDS-histogram; 8 global atomics per block) ----------
__global__ void k_zero(int* ctrl) {
  if (threadIdx.x < 16) ctrl[threadIdx.x] = 0;   // cnt[8], cursor[8]
}

__global__ void k_count(const int* __restrict__ ids, int* __restrict__ cnt) {
  __shared__ int l[NE];
  if (threadIdx.x < NE) l[threadIdx.x] = 0;
  __syncthreads();
  int t = blockIdx.x * 256 + threadIdx.x;
  atomicAdd(&l[expert_of(ids[t])], 1);
  __syncthreads();
  if (threadIdx.x < NE) atomicAdd(&cnt[threadIdx.x], l[threadIdx.x]);
}

__global__ void k_scan(const int* __restrict__ cnt, int* __restrict__ off) {
  if (threadIdx.x == 0 && blockIdx.x == 0) {
    int a = 0;
    for (int e = 0; e < NE; e++) { off[e] = a; a += (cnt[e] + 127) & ~127; }
    off[NE] = a;
  }
}

__global__ void k_fill(const int* __restrict__ ids, int* __restrict__ cursor,
                       const int* __restrict__ off, int* __restrict__ perm) {
  __shared__ int lcnt[NE], lbase[NE];
  if (threadIdx.x < NE) lcnt[threadIdx.x] = 0;
  __syncthreads();
  int t = blockIdx.x * 256 + threadIdx.x;
  int e = expert_of(ids[t]);
  int r = atomicAdd(&lcnt[e], 1);          // rank within block
  __syncthreads();
  if (threadIdx.x < NE)
    lbase[threadIdx.x] = atomicAdd(&cursor[threadIdx.x], lcnt[threadIdx.x]);
  __syncthreads();
  perm[off[e] + lbase[e] + r] = t;
}

// ---------------- conversions / weight build ----------------
__global__ void k_cvt_x(const float* __restrict__ src, unsigned short* __restrict__ dst) {
  size_t i = ((size_t)blockIdx.x * 256 + threadIdx.x) * 8;
  float4 a = *reinterpret_cast<const float4*>(src + i);
  float4 b = *reinterpret_cast<const float4*>(src + i + 4);
  u16x8 o;
  o[0]=f2bf(a.x); o[1]=f2bf(a.y); o[2]=f2bf(a.z); o[3]=f2bf(a.w);
  o[4]=f2bf(b.x); o[5]=f2bf(b.y); o[6]=f2bf(b.z); o[7]=f2bf(b.w);
  *reinterpret_cast<u16x8*>(dst + i) = o;
}

// row remap: mode 0 plain; mode 1 gate-interleave; mode 2 up-interleave
__device__ __forceinline__ int rowmap(int c, int mode) {
  if (mode == 0) return c;
  return ((c >> 4) << 5) + (c & 15) + (mode == 2 ? 16 : 0);
}

// transpose-convert: src f32 [R][C] per expert -> dst bf16 [rowmap(col)][src_row], stride HD
__global__ void k_transpose_cvt(const float* __restrict__ src0, unsigned short* __restrict__ dst0,
                                int C, int mode, size_t src_estride, size_t dst_estride) {
  const float* src = src0 + blockIdx.z * src_estride;
  unsigned short* dst = dst0 + blockIdx.z * dst_estride;
  __shared__ __attribute__((aligned(16))) float tile[32][33];
  int t = threadIdx.x;
  int r0 = blockIdx.y * 32, c0 = blockIdx.x * 32;
  int row = t >> 3, c4 = (t & 7) * 4;
  float4 v = *reinterpret_cast<const float4*>(src + (size_t)(r0 + row) * C + c0 + c4);
  tile[row][c4+0] = v.x; tile[row][c4+1] = v.y; tile[row][c4+2] = v.z; tile[row][c4+3] = v.w;
  __syncthreads();
  ushort4 o;
  o.x = f2bf(tile[c4+0][row]); o.y = f2bf(tile[c4+1][row]);
  o.z = f2bf(tile[c4+2][row]); o.w = f2bf(tile[c4+3][row]);
  int orow = rowmap(c0 + row, mode);
  *reinterpret_cast<ushort4*>(dst + (size_t)orow * HD + r0 + c4) = o;
}

// copy-convert: src f32 [rows][cols] -> dst row (1024+rowmap(r) if mode, else r), col dcol+c
__global__ void k_copy_cvt(const float* __restrict__ src, unsigned short* __restrict__ dst,
                           int cols, int mode, int dcol, size_t dst_estride) {
  size_t i = ((size_t)blockIdx.x * 256 + threadIdx.x) * 4;
  int r = (int)(i / cols), c = (int)(i % cols);
  int row = (mode == 0) ? r : (1024 + rowmap(r, mode));
  float4 v = *reinterpret_cast<const float4*>(src + i);
  ushort4 o; o.x=f2bf(v.x); o.y=f2bf(v.y); o.z=f2bf(v.z); o.w=f2bf(v.w);
  *reinterpret_cast<ushort4*>(dst + blockIdx.z * dst_estride
                              + (size_t)row * HD + dcol + c) = o;
}

// ---------------- GEMM 1: x @ W1(interleaved gate/up) + silu*mul -> inter ----------
// 512 thr = 8 waves (2M x 4N). Tile M=256, N=256 W1-rows, BK=64 (16 K-tiles).
// Region (16 KB) = 256 rows x 32 k, fragment-ordered: frag rb at rb*512 + lane*8.
// Stage inverse map: thread tid covers row (L*128 + wv*16 + tid&15), k ((tid>>4)&3)*8.
__global__ __launch_bounds__(512, 2) void k_gu(
    const unsigned short* __restrict__ xbf,
    const unsigned short* __restrict__ W1,   // [8][2048][1024]
    const int* __restrict__ perm, const int* __restrict__ cnt, const int* __restrict__ off,
    unsigned short* __restrict__ inter) {
  const int e = blockIdx.z;
  const int ce = cnt[e];
  const int m0 = blockIdx.y * 256;
  if (m0 >= ce) return;
  const int cep = (ce + 127) & ~127;
  const int n0 = blockIdx.x * 256;
  const int oe = off[e];
  __shared__ __attribute__((aligned(16))) unsigned short sm[65536];  // 128 KB
  const int tid = threadIdx.x;
  const int lane = tid & 63;
  const int wv = tid >> 6;
  const int wm = wv >> 2, wn = wv & 3;

  const int srow = wv * 16 + (tid & 15);      // staged row within 128-half
  const int srck = ((tid >> 4) & 3) * 8;      // staged k offset within K-half
  int ia = m0 + srow;        if (ia > ce - 1) ia = ce - 1;
  int ib = m0 + 128 + srow;  if (ib > ce - 1) ib = ce - 1;
  const unsigned short* pA0 = xbf + (size_t)perm[oe + ia] * HD + srck;
  const unsigned short* pA1 = xbf + (size_t)perm[oe + ib] * HD + srck;
  const unsigned short* pB0 = W1 + ((size_t)e << 21) + (size_t)(n0 + srow) * HD + srck;
  const unsigned short* pB1 = W1 + ((size_t)e << 21) + (size_t)(n0 + 128 + srow) * HD + srck;

  f32x4 acc[8][4];
#pragma unroll
  for (int mi = 0; mi < 8; mi++)
#pragma unroll
    for (int ni = 0; ni < 4; ni++) acc[mi][ni] = (f32x4){0.f, 0.f, 0.f, 0.f};

  auto stageA = [&](int b, int ks, int kt) {
    unsigned short* d = sm + b * 16384 + ks * 8192 + wv * 512;   // wave-uniform
    const int ko = kt * 64 + ks * 32;
    gld16(pA0 + ko, d);
    gld16(pA1 + ko, d + 4096);
  };
  auto stageB = [&](int b, int ks, int kt) {
    unsigned short* d = sm + 32768 + b * 16384 + ks * 8192 + wv * 512;
    const int ko = kt * 64 + ks * 32;
    gld16(pB0 + ko, d);
    gld16(pB1 + ko, d + 4096);
  };

  bf16x8 bb[4];
  auto phase = [&](int b, int ks, int mh) {
    asm volatile("s_barrier" ::: "memory");          // regions for this phase ready
    const unsigned short* Ar = sm + b * 16384 + ks * 8192;
    if (mh == 0) {
      const unsigned short* Br = sm + 32768 + b * 16384 + ks * 8192;
#pragma unroll
      for (int ni = 0; ni < 4; ni++)
        bb[ni] = *reinterpret_cast<const bf16x8*>(Br + (wn * 4 + ni) * 512 + lane * 8);
    }
    bf16x8 a[4];
#pragma unroll
    for (int j = 0; j < 4; j++)
      a[j] = *reinterpret_cast<const bf16x8*>(Ar + (wm * 8 + mh * 4 + j) * 512 + lane * 8);
    __builtin_amdgcn_s_setprio(1);
#pragma unroll
    for (int j = 0; j < 4; j++)
#pragma unroll
      for (int ni = 0; ni < 4; ni++)
        acc[mh * 4 + j][ni] = __builtin_amdgcn_mfma_f32_16x16x32_bf16(a[j], bb[ni], acc[mh * 4 + j][ni], 0, 0, 0);
    __builtin_amdgcn_s_setprio(0);
    asm volatile("s_barrier" ::: "memory");          // reads done: regions reusable
  };

  // prologue: tile0 all halves + tile1 K0 halves (6 half-tiles, 12 loads/wave-pair)
  stageA(0, 0, 0); stageB(0, 0, 0); stageA(0, 1, 0); stageB(0, 1, 0);
  stageA(1, 0, 1); stageB(1, 0, 1);
#pragma unroll 1
  for (int j = 0; j < 7; j++) {
    const int t1 = 2 * j + 1, t2 = 2 * j + 2, t3 = 2 * j + 3;
    stageA(1, 1, t1); asm volatile("s_waitcnt vmcnt(10)" ::: "memory"); phase(0, 0, 0);
    stageB(1, 1, t1);                                                   phase(0, 0, 1);
    stageA(0, 0, t2); asm volatile("s_waitcnt vmcnt(10)" ::: "memory"); phase(0, 1, 0);
    stageB(0, 0, t2);                                                   phase(0, 1, 1);
    stageA(0, 1, t2); asm volatile("s_waitcnt vmcnt(10)" ::: "memory"); phase(1, 0, 0);
    stageB(0, 1, t2);                                                   phase(1, 0, 1);
    stageA(1, 0, t3); asm volatile("s_waitcnt vmcnt(10)" ::: "memory"); phase(1, 1, 0);
    stageB(1, 0, t3);                                                   phase(1, 1, 1);
  }
  // peeled last pair (tiles 14, 15): drain 10 -> 8 -> 4 -> 0
  stageA(1, 1, 15); asm volatile("s_waitcnt vmcnt(10)" ::: "memory"); phase(0, 0, 0);
  stageB(1, 1, 15);                                                   phase(0, 0, 1);
  asm volatile("s_waitcnt vmcnt(8)" ::: "memory");                    phase(0, 1, 0);
                                                                      phase(0, 1, 1);
  asm volatile("s_waitcnt vmcnt(4)" ::: "memory");                    phase(1, 0, 0);
                                                                      phase(1, 0, 1);
  asm volatile("s_waitcnt vmcnt(0)" ::: "memory");                    phase(1, 1, 0);
                                                                      phase(1, 1, 1);

  // epilogue: n-frags alternate (gate, up) per 16; pair in-register
  const int colbase = (n0 + wn * 64) >> 1;
#pragma unroll
  for (int mi = 0; mi < 8; mi++)
#pragma unroll
    for (int p = 0; p < 2; p++)
#pragma unroll
      for (int r = 0; r < 4; r++) {
        int m = wm * 128 + mi * 16 + (lane >> 4) * 4 + r;
        if (m0 + m < cep) {
          float g = acc[mi][2 * p][r];
          float u = acc[mi][2 * p + 1][r];
          float sv = g / (1.f + __expf(-g)) * u;
          inter[(size_t)(oe + m0 + m) * HD + colbase + p * 16 + (lane & 15)] = f2bf(sv);
        }
      }
}

// ---------------- GEMM 2: inter @ Dcat -> out (scatter rows via perm) ----------------
// Same 8-phase pipeline. Tile M=256, N=256 out cols, BK=64.
__global__ __launch_bounds__(512, 2) void k_down(
    const unsigned short* __restrict__ inter,
    const unsigned short* __restrict__ Dt,   // [8][1024][1024] B^T
    const int* __restrict__ perm, const int* __restrict__ cnt, const int* __restrict__ off,
    float* __restrict__ out) {
  const int e = blockIdx.z;
  const int ce = cnt[e];
  const int m0 = blockIdx.y * 256;
  if (m0 >= ce) return;
  const int cep = (ce + 127) & ~127;
  const int n0 = blockIdx.x * 256;
  const int oe = off[e];
  __shared__ __attribute__((aligned(16))) unsigned short sm[65536];
  const int tid = threadIdx.x;
  const int lane = tid & 63;
  const int wv = tid >> 6;
  const int wm = wv >> 2, wn = wv & 3;

  const int srow = wv * 16 + (tid & 15);
  const int srck = ((tid >> 4) & 3) * 8;
  int ia = m0 + srow;        if (ia > cep - 1) ia = cep - 1;
  int ib = m0 + 128 + srow;  if (ib > cep - 1) ib = cep - 1;
  const unsigned short* pA0 = inter + (size_t)(oe + ia) * HD + srck;
  const unsigned short* pA1 = inter + (size_t)(oe + ib) * HD + srck;
  const unsigned short* pB0 = Dt + ((size_t)e << 20) + (size_t)(n0 + srow) * HD + srck;
  const unsigned short* pB1 = Dt + ((size_t)e << 20) + (size_t)(n0 + 128 + srow) * HD + srck;

  f32x4 acc[8][4];
#pragma unroll
  for (int mi = 0; mi < 8; mi++)
#pragma unroll
    for (int ni = 0; ni < 4; ni++) acc[mi][ni] = (f32x4){0.f, 0.f, 0.f, 0.f};

  auto stageA = [&](int b, int ks, int kt) {
    unsigned short* d = sm + b * 16384 + ks * 8192 + wv * 512;
    const int ko = kt * 64 + ks * 32;
    gld16(pA0 + ko, d);
    gld16(pA1 + ko, d + 4096);
  };
  auto stageB = [&](int b, int ks, int kt) {
    unsigned short* d = sm + 32768 + b * 16384 + ks * 8192 + wv * 512;
    const int ko = kt * 64 + ks * 32;
    gld16(pB0 + ko, d);
    gld16(pB1 + ko, d + 4096);
  };

  bf16x8 bb[4];
  auto phase = [&](int b, int ks, int mh) {
    asm volatile("s_barrier" ::: "memory");
    const unsigned short* Ar = sm + b * 16384 + ks * 8192;
    if (mh == 0) {
      const unsigned short* Br = sm + 32768 + b * 16384 + ks * 8192;
#pragma unroll
      for (int ni = 0; ni < 4; ni++)
        bb[ni] = *reinterpret_cast<const bf16x8*>(Br + (wn * 4 + ni) * 512 + lane * 8);
    }
    bf16x8 a[4];
#pragma unroll
    for (int j = 0; j < 4; j++)
      a[j] = *reinterpret_cast<const bf16x8*>(Ar + (wm * 8 + mh * 4 + j) * 512 + lane * 8);
    __builtin_amdgcn_s_setprio(1);
#pragma unroll
    for (int j = 0; j < 4; j++)
#pragma unroll
      for (int ni = 0; ni < 4; ni++)
        acc[mh * 4 + j][ni] = __builtin_amdgcn_mfma_f32_16x16x32_bf16(a[j], bb[ni], acc[mh * 4 + j][ni], 0, 0, 0);
    __builtin_amdgcn_s_setprio(0);
    asm volatile("s_barrier" ::: "memory");
  };

  stageA(0, 0, 0); stageB(0, 0, 0); stageA(0, 1, 0); stageB(0, 1, 0);
  stageA(1, 0, 1); stageB(1, 0, 1);
#pragma unroll 1
  for (int j = 0; j < 7; j++) {
    const int t1 = 2 * j + 1, t2 = 2 * j + 2, t3 = 2 * j + 3;
    stageA(1, 1, t1); asm volatile("s_waitcnt vmcnt(10)" ::: "memory"); phase(0, 0, 0);
    stageB(1, 1, t1);                                                   phase(0, 0, 1);
    stageA(0, 0, t2); asm volatile("s_waitcnt vmcnt(10)" ::: "memory"); phase(0, 1, 0);
    stageB(0, 0, t2);                                                   phase(0, 1, 1);
    stageA(0, 1, t2); asm volatile("s_waitcnt vmcnt(10)" ::: "memory"); phase(1, 0, 0);
    stageB(0, 1, t2);                                                   phase(1, 0, 1);
    stageA(1, 0, t3); asm volatile("s_waitcnt vmcnt(10)" ::: "memory"); phase(1, 1, 0);
    stageB(1, 0, t3);                                                   phase(1, 1, 1);
  }
  stageA(1, 1, 15); asm volatile("s_waitcnt vmcnt(10)" ::: "memory"); phase(0, 0, 0);
  stageB(1, 1, 15);                                                   phase(0, 0, 1);
  asm volatile("s_waitcnt vmcnt(8)" ::: "memory");                    phase(0, 1, 0);
                                                                      phase(0, 1, 1);
  asm volatile("s_waitcnt vmcnt(4)" ::: "memory");                    phase(1, 0, 0);
                                                                      phase(1, 0, 1);
  asm volatile("s_waitcnt vmcnt(0)" ::: "memory");                    phase(1, 1, 0);
                                                                      phase(1, 1, 1);

#pragma unroll
  for (int mi = 0; mi < 8; mi++)
#pragma unroll
    for (int r = 0; r < 4; r++) {
      int m = wm * 128 + mi * 16 + (lane >> 4) * 4 + r;
      int gm = m0 + m;
      if (gm < ce) {                      // only real tokens scatter
        int t = perm[oe + gm];
#pragma unroll
        for (int ni = 0; ni < 4; ni++)
          out[(size_t)t * HD + n0 + wn * 64 + ni * 16 + (lane & 15)] = acc[mi][ni][r];
      }
    }
}

// ---------------- naive fp32 fallback (only if ws too small) ----------------
__global__ __launch_bounds__(256) void k_naive(
    const float* __restrict__ x, const int* __restrict__ ids,
    const float* __restrict__ gw, const float* __restrict__ uw, const float* __restrict__ dw,
    const float* __restrict__ sgw, const float* __restrict__ suw, const float* __restrict__ sdw,
    float* __restrict__ out) {
  const int t = blockIdx.x;
  const int tid = threadIdx.x;
  __shared__ float sx[1024];
  __shared__ float si[1024];
  for (int i = tid; i < 1024; i += 256) sx[i] = x[(size_t)t * 1024 + i];
  const int e = expert_of(ids[t]);
  __syncthreads();
  const float* gwe = gw + (size_t)e * 1024 * 512;
  const float* uwe = uw + (size_t)e * 1024 * 512;
  for (int j = tid; j < 512; j += 256) {
    float g = 0, u = 0, sg = 0, su = 0;
    for (int k = 0; k < 1024; k++) {
      float xv = sx[k];
      g += xv * gwe[(size_t)k * 512 + j];
      u += xv * uwe[(size_t)k * 512 + j];
      sg += xv * sgw[(size_t)j * 1024 + k];
      su += xv * suw[(size_t)j * 1024 + k];
    }
    si[j] = g / (1.f + __expf(-g)) * u;
    si[512 + j] = sg / (1.f + __expf(-sg)) * su;
  }
  __syncthreads();
  const float* dwe = dw + (size_t)e * 512 * 1024;
  for (int n = tid; n < 1024; n += 256) {
    float a = 0;
    for (int k = 0; k < 512; k++)
      a += si[k] * dwe[(size_t)k * 1024 + n] + si[512 + k] * sdw[(size_t)n * 512 + k];
    out[(size_t)t * 1024 + n] = a;
  }
}

extern "C" void kernel_launch(void* const* d_in, const int* in_sizes, int n_in,
                              void* d_out, int out_size, void* d_ws, size_t ws_size,
                              hipStream_t stream) {
  const float* x = (const float*)d_in[0];
  const int* ids = (const int*)d_in[1];          // harness passes integers as int32
  const float* gw = (const float*)d_in[2];
  const float* uw = (const float*)d_in[3];
  const float* dw = (const float*)d_in[4];
  const float* sgw = (const float*)d_in[5];
  const float* suw = (const float*)d_in[6];
  const float* sdw = (const float*)d_in[7];
  float* out = (float*)d_out;

  const size_t REQ = 186908672ull;
  if (ws_size < REQ) {
    k_naive<<<N_TOK, 256, 0, stream>>>(x, ids, gw, uw, dw, sgw, suw, sdw, out);
    return;
  }

  char* ws = (char*)d_ws;
  int* ctrl = (int*)ws;                                   // cnt[8] | cursor[8] | off[9]
  int* perm = (int*)(ws + 1024);                          // 33792 ints
  unsigned short* xbf = (unsigned short*)(ws + 262144);   // [32768][1024]
  unsigned short* W1 = (unsigned short*)(ws + 67371008ull);   // [8][2048][1024] interleaved
  unsigned short* Dt = (unsigned short*)(ws + 100925440ull);  // [8][1024][1024]
  unsigned short* inter = (unsigned short*)(ws + 117702656ull); // [33792][1024]

  k_zero<<<1, 64, 0, stream>>>(ctrl);
  k_count<<<128, 256, 0, stream>>>(ids, ctrl);
  k_scan<<<1, 64, 0, stream>>>(ctrl, ctrl + 16);
  k_fill<<<128, 256, 0, stream>>>(ids, ctrl + 8, ctrl + 16, perm);
  k_cvt_x<<<16384, 256, 0, stream>>>(x, xbf);
  // routed weights: gate/up [1024][512] -> W1 interleaved rows; down [512][1024] -> Dt plain
  k_transpose_cvt<<<dim3(16, 32, 8), 256, 0, stream>>>(gw, W1, 512, 1,
                                                       (size_t)1024 * 512, (size_t)1 << 21);
  k_transpose_cvt<<<dim3(16, 32, 8), 256, 0, stream>>>(uw, W1, 512, 2,
                                                       (size_t)1024 * 512, (size_t)1 << 21);
  k_transpose_cvt<<<dim3(32, 16, 8), 256, 0, stream>>>(dw, Dt, 1024, 0,
                                                       (size_t)512 * 1024, (size_t)1 << 20);
  // shared weights appended (replicated per expert)
  k_copy_cvt<<<dim3(512, 1, 8), 256, 0, stream>>>(sgw, W1, 1024, 1, 0, (size_t)1 << 21);
  k_copy_cvt<<<dim3(512, 1, 8), 256, 0, stream>>>(suw, W1, 1024, 2, 0, (size_t)1 << 21);
  k_copy_cvt<<<dim3(512, 1, 8), 256, 0, stream>>>(sdw, Dt, 512, 0, 512, (size_t)1 << 20);
  // grouped GEMMs (256^2 tiles, 8-phase counted-vmcnt pipeline)
  k_gu<<<dim3(8, 128, 8), 512, 0, stream>>>(xbf, W1, perm, ctrl, ctrl + 16, inter);
  k_down<<<dim3(4, 128, 8), 512, 0, stream>>>(inter, Dt, perm, ctrl, ctrl + 16, out);
}

// Round 10
// 391.038 us; speedup vs baseline: 1.0627x; 1.0133x over previous
//
#include <hip/hip_runtime.h>
#include <hip/hip_bf16.h>

// TokenRoutedMLP: N=32768 tokens, H=1024, 8 routed experts (id%8) + shared expert.
// Grouped bf16 MFMA GEMMs; shared expert folded via concat weights; gate/up
// interleaved by 16 cols in W1 so silu pairing is in-register.
// GEMM: 8-phase schedule WITH one-phase ds_read read-ahead (m201-faithful).
// 256x256 tile, BK=64, 8 waves. LDS 128 KiB = 2 buf x {A,B} x 2 K-half regions,
// fragment-ordered (conflict-free ds_read_b128, verified R7).
// Phase: {stage 1 half-tile; [vmcnt(8) even phases]; s_barrier;
//         MFMA(regs read last phase); ds_read next phase's frags; s_barrier}.
// Per-wave vmcnt ledger: prologue 12 loads, VM(8) at every even phase confirms
// exactly the 2 regions read in that body; in-flight 8..12; tail 8->4->0.
// global_load_lds: LDS dest wave-uniform base + lane*16B (m104/m108).

#define N_TOK 32768
#define HD 1024
#define NE 8

typedef __attribute__((ext_vector_type(8))) short bf16x8;
typedef __attribute__((ext_vector_type(8))) unsigned short u16x8;
typedef __attribute__((ext_vector_type(4))) float f32x4;

#define BAR() asm volatile("s_barrier" ::: "memory")
#define VM8() asm volatile("s_waitcnt vmcnt(8)" ::: "memory")

__device__ __forceinline__ unsigned short f2bf(float f) {
  unsigned int x = __float_as_uint(f);
  x += 0x7fffu + ((x >> 16) & 1u);   // RTNE
  return (unsigned short)(x >> 16);
}

__device__ __forceinline__ void gld16(const unsigned short* g, unsigned short* l) {
  __builtin_amdgcn_global_load_lds(
      (const __attribute__((address_space(1))) unsigned int*)g,
      (__attribute__((address_space(3))) unsigned int*)l,
      16, 0, 0);
}

__device__ __forceinline__ int expert_of(int id) {
  int v = id < 0 ? 0 : (id > 99999 ? 99999 : id);
  return v & 7;
}

// ---------------- routing (LDS-histogram; 8 global atomics per block) ----------
__global__ void k_zero(int* ctrl) {
  if (threadIdx.x < 16) ctrl[threadIdx.x] = 0;   // cnt[8], cursor[8]
}

__global__ void k_count(const int* __restrict__ ids, int* __restrict__ cnt) {
  __shared__ int l[NE];
  if (threadIdx.x < NE) l[threadIdx.x] = 0;
  __syncthreads();
  int t = blockIdx.x * 256 + threadIdx.x;
  atomicAdd(&l[expert_of(ids[t])], 1);
  __syncthreads();
  if (threadIdx.x < NE) atomicAdd(&cnt[threadIdx.x], l[threadIdx.x]);
}

__global__ void k_scan(const int* __restrict__ cnt, int* __restrict__ off) {
  if (threadIdx.x == 0 && blockIdx.x == 0) {
    int a = 0;
    for (int e = 0; e < NE; e++) { off[e] = a; a += (cnt[e] + 127) & ~127; }
    off[NE] = a;
  }
}

__global__ void k_fill(const int* __restrict__ ids, int* __restrict__ cursor,
                       const int* __restrict__ off, int* __restrict__ perm) {
  __shared__ int lcnt[NE], lbase[NE];
  if (threadIdx.x < NE) lcnt[threadIdx.x] = 0;
  __syncthreads();
  int t = blockIdx.x * 256 + threadIdx.x;
  int e = expert_of(ids[t]);
  int r = atomicAdd(&lcnt[e], 1);          // rank within block
  __syncthreads();
  if (threadIdx.x < NE)
    lbase[threadIdx.x] = atomicAdd(&cursor[threadIdx.x], lcnt[threadIdx.x]);
  __syncthreads();
  perm[off[e] + lbase[e] + r] = t;
}

// ---------------- conversions / weight build ----------------
__global__ void k_cvt_x(const float* __restrict__ src, unsigned short* __restrict__ dst) {
  size_t i = ((size_t)blockIdx.x * 256 + threadIdx.x) * 8;
  float4 a = *reinterpret_cast<const float4*>(src + i);
  float4 b = *reinterpret_cast<const float4*>(src + i + 4);
  u16x8 o;
  o[0]=f2bf(a.x); o[1]=f2bf(a.y); o[2]=f2bf(a.z); o[3]=f2bf(a.w);
  o[4]=f2bf(b.x); o[5]=f2bf(b.y); o[6]=f2bf(b.z); o[7]=f2bf(b.w);
  *reinterpret_cast<u16x8*>(dst + i) = o;
}

// row remap: mode 0 plain; mode 1 gate-interleave; mode 2 up-interleave
__device__ __forceinline__ int rowmap(int c, int mode) {
  if (mode == 0) return c;
  return ((c >> 4) << 5) + (c & 15) + (mode == 2 ? 16 : 0);
}

// transpose-convert: src f32 [R][C] per expert -> dst bf16 [rowmap(col)][src_row], stride HD
__global__ void k_transpose_cvt(const float* __restrict__ src0, unsigned short* __restrict__ dst0,
                                int C, int mode, size_t src_estride, size_t dst_estride) {
  const float* src = src0 + blockIdx.z * src_estride;
  unsigned short* dst = dst0 + blockIdx.z * dst_estride;
  __shared__ __attribute__((aligned(16))) float tile[32][33];
  int t = threadIdx.x;
  int r0 = blockIdx.y * 32, c0 = blockIdx.x * 32;
  int row = t >> 3, c4 = (t & 7) * 4;
  float4 v = *reinterpret_cast<const float4*>(src + (size_t)(r0 + row) * C + c0 + c4);
  tile[row][c4+0] = v.x; tile[row][c4+1] = v.y; tile[row][c4+2] = v.z; tile[row][c4+3] = v.w;
  __syncthreads();
  ushort4 o;
  o.x = f2bf(tile[c4+0][row]); o.y = f2bf(tile[c4+1][row]);
  o.z = f2bf(tile[c4+2][row]); o.w = f2bf(tile[c4+3][row]);
  int orow = rowmap(c0 + row, mode);
  *reinterpret_cast<ushort4*>(dst + (size_t)orow * HD + r0 + c4) = o;
}

// copy-convert: src f32 [rows][cols] -> dst row (1024+rowmap(r) if mode, else r), col dcol+c
__global__ void k_copy_cvt(const float* __restrict__ src, unsigned short* __restrict__ dst,
                           int cols, int mode, int dcol, size_t dst_estride) {
  size_t i = ((size_t)blockIdx.x * 256 + threadIdx.x) * 4;
  int r = (int)(i / cols), c = (int)(i % cols);
  int row = (mode == 0) ? r : (1024 + rowmap(r, mode));
  float4 v = *reinterpret_cast<const float4*>(src + i);
  ushort4 o; o.x=f2bf(v.x); o.y=f2bf(v.y); o.z=f2bf(v.z); o.w=f2bf(v.w);
  *reinterpret_cast<ushort4*>(dst + blockIdx.z * dst_estride
                              + (size_t)row * HD + dcol + c) = o;
}

// ---------------- GEMM 1: x @ W1(interleaved gate/up) + silu*mul -> inter ----------
__global__ __launch_bounds__(512, 2) void k_gu(
    const unsigned short* __restrict__ xbf,
    const unsigned short* __restrict__ W1,   // [8][2048][1024]
    const int* __restrict__ perm, const int* __restrict__ cnt, const int* __restrict__ off,
    unsigned short* __restrict__ inter) {
  const int e = blockIdx.z;
  const int ce = cnt[e];
  const int m0 = blockIdx.y * 256;
  if (m0 >= ce) return;
  const int cep = (ce + 127) & ~127;
  const int n0 = blockIdx.x * 256;
  const int oe = off[e];
  __shared__ __attribute__((aligned(16))) unsigned short sm[65536];  // 128 KB
  const int tid = threadIdx.x;
  const int lane = tid & 63;
  const int wv = tid >> 6;
  const int wm = wv >> 2, wn = wv & 3;

  const int srow = wv * 16 + (tid & 15);      // staged row within 128-half
  const int srck = ((tid >> 4) & 3) * 8;      // staged k offset within K-half
  int ia = m0 + srow;        if (ia > ce - 1) ia = ce - 1;
  int ib = m0 + 128 + srow;  if (ib > ce - 1) ib = ce - 1;
  const unsigned short* pA0 = xbf + (size_t)perm[oe + ia] * HD + srck;
  const unsigned short* pA1 = xbf + (size_t)perm[oe + ib] * HD + srck;
  const unsigned short* pB0 = W1 + ((size_t)e << 21) + (size_t)(n0 + srow) * HD + srck;
  const unsigned short* pB1 = W1 + ((size_t)e << 21) + (size_t)(n0 + 128 + srow) * HD + srck;

  f32x4 acc[8][4];
#pragma unroll
  for (int mi = 0; mi < 8; mi++)
#pragma unroll
    for (int ni = 0; ni < 4; ni++) acc[mi][ni] = (f32x4){0.f, 0.f, 0.f, 0.f};

  auto stageA = [&](int b, int ks, int kt) {
    unsigned short* d = sm + b * 16384 + ks * 8192 + wv * 512;   // wave-uniform
    const int ko = kt * 64 + ks * 32;
    gld16(pA0 + ko, d);
    gld16(pA1 + ko, d + 4096);
  };
  auto stageB = [&](int b, int ks, int kt) {
    unsigned short* d = sm + 32768 + b * 16384 + ks * 8192 + wv * 512;
    const int ko = kt * 64 + ks * 32;
    gld16(pB0 + ko, d);
    gld16(pB1 + ko, d + 4096);
  };
  auto rdA = [&](bf16x8* dst, int b, int ks, int mh) {
    const unsigned short* Ar = sm + b * 16384 + ks * 8192;
#pragma unroll
    for (int j = 0; j < 4; j++)
      dst[j] = *reinterpret_cast<const bf16x8*>(Ar + (wm * 8 + mh * 4 + j) * 512 + lane * 8);
  };
  auto rdB = [&](bf16x8* dst, int b, int ks) {
    const unsigned short* Br = sm + 32768 + b * 16384 + ks * 8192;
#pragma unroll
    for (int ni = 0; ni < 4; ni++)
      dst[ni] = *reinterpret_cast<const bf16x8*>(Br + (wn * 4 + ni) * 512 + lane * 8);
  };
  auto mf = [&](int mh, const bf16x8* a, const bf16x8* bb) {
    __builtin_amdgcn_s_setprio(1);
#pragma unroll
    for (int j = 0; j < 4; j++)
#pragma unroll
      for (int ni = 0; ni < 4; ni++)
        acc[mh * 4 + j][ni] = __builtin_amdgcn_mfma_f32_16x16x32_bf16(a[j], bb[ni], acc[mh * 4 + j][ni], 0, 0, 0);
    __builtin_amdgcn_s_setprio(0);
  };

  bf16x8 aX[4], aY[4], bbX[4], bbY[4];

  // prologue: 12 loads; confirm A00,B00; pre-read phase-1 frags
  stageA(0, 0, 0); stageB(0, 0, 0); stageA(0, 1, 0); stageB(0, 1, 0);
  stageA(1, 0, 1); stageB(1, 0, 1);
  VM8(); BAR();
  rdA(aX, 0, 0, 0); rdB(bbX, 0, 0);

#pragma unroll 1
  for (int j = 0; j < 7; j++) {
    const int t1 = 2 * j + 1, t2 = 2 * j + 2, t3 = 2 * j + 3;
    stageA(1,1,t1);        BAR(); mf(0, aX, bbX); rdA(aY,0,0,1);                  BAR();
    stageB(1,1,t1); VM8(); BAR(); mf(1, aY, bbX); rdA(aX,0,1,0); rdB(bbY,0,1);    BAR();
    stageA(0,0,t2);        BAR(); mf(0, aX, bbY); rdA(aY,0,1,1);                  BAR();
    stageB(0,0,t2); VM8(); BAR(); mf(1, aY, bbY); rdA(aX,1,0,0); rdB(bbX,1,0);    BAR();
    stageA(0,1,t2);        BAR(); mf(0, aX, bbX); rdA(aY,1,0,1);                  BAR();
    stageB(0,1,t2); VM8(); BAR(); mf(1, aY, bbX); rdA(aX,1,1,0); rdB(bbY,1,1);    BAR();
    stageA(1,0,t3);        BAR(); mf(0, aX, bbY); rdA(aY,1,1,1);                  BAR();
    stageB(1,0,t3); VM8(); BAR(); mf(1, aY, bbY); rdA(aX,0,0,0); rdB(bbX,0,0);    BAR();
  }
  // tail: tiles 14 (b0), 15 (b1); drain 8 -> 4 -> 0
  stageA(1,1,15);        BAR(); mf(0, aX, bbX); rdA(aY,0,0,1);                  BAR();
  stageB(1,1,15); VM8(); BAR(); mf(1, aY, bbX); rdA(aX,0,1,0); rdB(bbY,0,1);    BAR();
                         BAR(); mf(0, aX, bbY); rdA(aY,0,1,1);                  BAR();
  asm volatile("s_waitcnt vmcnt(4)" ::: "memory");
                         BAR(); mf(1, aY, bbY); rdA(aX,1,0,0); rdB(bbX,1,0);    BAR();
                         BAR(); mf(0, aX, bbX); rdA(aY,1,0,1);                  BAR();
  asm volatile("s_waitcnt vmcnt(0)" ::: "memory");
                         BAR(); mf(1, aY, bbX); rdA(aX,1,1,0); rdB(bbY,1,1);    BAR();
                         BAR(); mf(0, aX, bbY); rdA(aY,1,1,1);                  BAR();
                         BAR(); mf(1, aY, bbY);

  // epilogue: n-frags alternate (gate, up) per 16; pair in-register
  const int colbase = (n0 + wn * 64) >> 1;
#pragma unroll
  for (int mi = 0; mi < 8; mi++)
#pragma unroll
    for (int p = 0; p < 2; p++)
#pragma unroll
      for (int r = 0; r < 4; r++) {
        int m = wm * 128 + mi * 16 + (lane >> 4) * 4 + r;
        if (m0 + m < cep) {
          float g = acc[mi][2 * p][r];
          float u = acc[mi][2 * p + 1][r];
          float sv = g / (1.f + __expf(-g)) * u;
          inter[(size_t)(oe + m0 + m) * HD + colbase + p * 16 + (lane & 15)] = f2bf(sv);
        }
      }
}

// ---------------- GEMM 2: inter @ Dcat -> out (scatter rows via perm) ----------------
__global__ __launch_bounds__(512, 2) void k_down(
    const unsigned short* __restrict__ inter,
    const unsigned short* __restrict__ Dt,   // [8][1024][1024] B^T
    const int* __restrict__ perm, const int* __restrict__ cnt, const int* __restrict__ off,
    float* __restrict__ out) {
  const int e = blockIdx.z;
  const int ce = cnt[e];
  const int m0 = blockIdx.y * 256;
  if (m0 >= ce) return;
  const int cep = (ce + 127) & ~127;
  const int n0 = blockIdx.x * 256;
  const int oe = off[e];
  __shared__ __attribute__((aligned(16))) unsigned short sm[65536];
  const int tid = threadIdx.x;
  const int lane = tid & 63;
  const int wv = tid >> 6;
  const int wm = wv >> 2, wn = wv & 3;

  const int srow = wv * 16 + (tid & 15);
  const int srck = ((tid >> 4) & 3) * 8;
  int ia = m0 + srow;        if (ia > cep - 1) ia = cep - 1;
  int ib = m0 + 128 + srow;  if (ib > cep - 1) ib = cep - 1;
  const unsigned short* pA0 = inter + (size_t)(oe + ia) * HD + srck;
  const unsigned short* pA1 = inter + (size_t)(oe + ib) * HD + srck;
  const unsigned short* pB0 = Dt + ((size_t)e << 20) + (size_t)(n0 + srow) * HD + srck;
  const unsigned short* pB1 = Dt + ((size_t)e << 20) + (size_t)(n0 + 128 + srow) * HD + srck;

  f32x4 acc[8][4];
#pragma unroll
  for (int mi = 0; mi < 8; mi++)
#pragma unroll
    for (int ni = 0; ni < 4; ni++) acc[mi][ni] = (f32x4){0.f, 0.f, 0.f, 0.f};

  auto stageA = [&](int b, int ks, int kt) {
    unsigned short* d = sm + b * 16384 + ks * 8192 + wv * 512;
    const int ko = kt * 64 + ks * 32;
    gld16(pA0 + ko, d);
    gld16(pA1 + ko, d + 4096);
  };
  auto stageB = [&](int b, int ks, int kt) {
    unsigned short* d = sm + 32768 + b * 16384 + ks * 8192 + wv * 512;
    const int ko = kt * 64 + ks * 32;
    gld16(pB0 + ko, d);
    gld16(pB1 + ko, d + 4096);
  };
  auto rdA = [&](bf16x8* dst, int b, int ks, int mh) {
    const unsigned short* Ar = sm + b * 16384 + ks * 8192;
#pragma unroll
    for (int j = 0; j < 4; j++)
      dst[j] = *reinterpret_cast<const bf16x8*>(Ar + (wm * 8 + mh * 4 + j) * 512 + lane * 8);
  };
  auto rdB = [&](bf16x8* dst, int b, int ks) {
    const unsigned short* Br = sm + 32768 + b * 16384 + ks * 8192;
#pragma unroll
    for (int ni = 0; ni < 4; ni++)
      dst[ni] = *reinterpret_cast<const bf16x8*>(Br + (wn * 4 + ni) * 512 + lane * 8);
  };
  auto mf = [&](int mh, const bf16x8* a, const bf16x8* bb) {
    __builtin_amdgcn_s_setprio(1);
#pragma unroll
    for (int j = 0; j < 4; j++)
#pragma unroll
      for (int ni = 0; ni < 4; ni++)
        acc[mh * 4 + j][ni] = __builtin_amdgcn_mfma_f32_16x16x32_bf16(a[j], bb[ni], acc[mh * 4 + j][ni], 0, 0, 0);
    __builtin_amdgcn_s_setprio(0);
  };

  bf16x8 aX[4], aY[4], bbX[4], bbY[4];

  stageA(0, 0, 0); stageB(0, 0, 0); stageA(0, 1, 0); stageB(0, 1, 0);
  stageA(1, 0, 1); stageB(1, 0, 1);
  VM8(); BAR();
  rdA(aX, 0, 0, 0); rdB(bbX, 0, 0);

#pragma unroll 1
  for (int j = 0; j < 7; j++) {
    const int t1 = 2 * j + 1, t2 = 2 * j + 2, t3 = 2 * j + 3;
    stageA(1,1,t1);        BAR(); mf(0, aX, bbX); rdA(aY,0,0,1);                  BAR();
    stageB(1,1,t1); VM8(); BAR(); mf(1, aY, bbX); rdA(aX,0,1,0); rdB(bbY,0,1);    BAR();
    stageA(0,0,t2);        BAR(); mf(0, aX, bbY); rdA(aY,0,1,1);                  BAR();
    stageB(0,0,t2); VM8(); BAR(); mf(1, aY, bbY); rdA(aX,1,0,0); rdB(bbX,1,0);    BAR();
    stageA(0,1,t2);        BAR(); mf(0, aX, bbX); rdA(aY,1,0,1);                  BAR();
    stageB(0,1,t2); VM8(); BAR(); mf(1, aY, bbX); rdA(aX,1,1,0); rdB(bbY,1,1);    BAR();
    stageA(1,0,t3);        BAR(); mf(0, aX, bbY); rdA(aY,1,1,1);                  BAR();
    stageB(1,0,t3); VM8(); BAR(); mf(1, aY, bbY); rdA(aX,0,0,0); rdB(bbX,0,0);    BAR();
  }
  stageA(1,1,15);        BAR(); mf(0, aX, bbX); rdA(aY,0,0,1);                  BAR();
  stageB(1,1,15); VM8(); BAR(); mf(1, aY, bbX); rdA(aX,0,1,0); rdB(bbY,0,1);    BAR();
                         BAR(); mf(0, aX, bbY); rdA(aY,0,1,1);                  BAR();
  asm volatile("s_waitcnt vmcnt(4)" ::: "memory");
                         BAR(); mf(1, aY, bbY); rdA(aX,1,0,0); rdB(bbX,1,0);    BAR();
                         BAR(); mf(0, aX, bbX); rdA(aY,1,0,1);                  BAR();
  asm volatile("s_waitcnt vmcnt(0)" ::: "memory");
                         BAR(); mf(1, aY, bbX); rdA(aX,1,1,0); rdB(bbY,1,1);    BAR();
                         BAR(); mf(0, aX, bbY); rdA(aY,1,1,1);                  BAR();
                         BAR(); mf(1, aY, bbY);

#pragma unroll
  for (int mi = 0; mi < 8; mi++)
#pragma unroll
    for (int r = 0; r < 4; r++) {
      int m = wm * 128 + mi * 16 + (lane >> 4) * 4 + r;
      int gm = m0 + m;
      if (gm < ce) {                      // only real tokens scatter
        int t = perm[oe + gm];
#pragma unroll
        for (int ni = 0; ni < 4; ni++)
          out[(size_t)t * HD + n0 + wn * 64 + ni * 16 + (lane & 15)] = acc[mi][ni][r];
      }
    }
}

// ---------------- naive fp32 fallback (only if ws too small) ----------------
__global__ __launch_bounds__(256) void k_naive(
    const float* __restrict__ x, const int* __restrict__ ids,
    const float* __restrict__ gw, const float* __restrict__ uw, const float* __restrict__ dw,
    const float* __restrict__ sgw, const float* __restrict__ suw, const float* __restrict__ sdw,
    float* __restrict__ out) {
  const int t = blockIdx.x;
  const int tid = threadIdx.x;
  __shared__ float sx[1024];
  __shared__ float si[1024];
  for (int i = tid; i < 1024; i += 256) sx[i] = x[(size_t)t * 1024 + i];
  const int e = expert_of(ids[t]);
  __syncthreads();
  const float* gwe = gw + (size_t)e * 1024 * 512;
  const float* uwe = uw + (size_t)e * 1024 * 512;
  for (int j = tid; j < 512; j += 256) {
    float g = 0, u = 0, sg = 0, su = 0;
    for (int k = 0; k < 1024; k++) {
      float xv = sx[k];
      g += xv * gwe[(size_t)k * 512 + j];
      u += xv * uwe[(size_t)k * 512 + j];
      sg += xv * sgw[(size_t)j * 1024 + k];
      su += xv * suw[(size_t)j * 1024 + k];
    }
    si[j] = g / (1.f + __expf(-g)) * u;
    si[512 + j] = sg / (1.f + __expf(-sg)) * su;
  }
  __syncthreads();
  const float* dwe = dw + (size_t)e * 512 * 1024;
  for (int n = tid; n < 1024; n += 256) {
    float a = 0;
    for (int k = 0; k < 512; k++)
      a += si[k] * dwe[(size_t)k * 1024 + n] + si[512 + k] * sdw[(size_t)n * 512 + k];
    out[(size_t)t * 1024 + n] = a;
  }
}

extern "C" void kernel_launch(void* const* d_in, const int* in_sizes, int n_in,
                              void* d_out, int out_size, void* d_ws, size_t ws_size,
                              hipStream_t stream) {
  const float* x = (const float*)d_in[0];
  const int* ids = (const int*)d_in[1];          // harness passes integers as int32
  const float* gw = (const float*)d_in[2];
  const float* uw = (const float*)d_in[3];
  const float* dw = (const float*)d_in[4];
  const float* sgw = (const float*)d_in[5];
  const float* suw = (const float*)d_in[6];
  const float* sdw = (const float*)d_in[7];
  float* out = (float*)d_out;

  const size_t REQ = 186908672ull;
  if (ws_size < REQ) {
    k_naive<<<N_TOK, 256, 0, stream>>>(x, ids, gw, uw, dw, sgw, suw, sdw, out);
    return;
  }

  char* ws = (char*)d_ws;
  int* ctrl = (int*)ws;                                   // cnt[8] | cursor[8] | off[9]
  int* perm = (int*)(ws + 1024);                          // 33792 ints
  unsigned short* xbf = (unsigned short*)(ws + 262144);   // [32768][1024]
  unsigned short* W1 = (unsigned short*)(ws + 67371008ull);   // [8][2048][1024] interleaved
  unsigned short* Dt = (unsigned short*)(ws + 100925440ull);  // [8][1024][1024]
  unsigned short* inter = (unsigned short*)(ws + 117702656ull); // [33792][1024]

  k_zero<<<1, 64, 0, stream>>>(ctrl);
  k_count<<<128, 256, 0, stream>>>(ids, ctrl);
  k_scan<<<1, 64, 0, stream>>>(ctrl, ctrl + 16);
  k_fill<<<128, 256, 0, stream>>>(ids, ctrl + 8, ctrl + 16, perm);
  k_cvt_x<<<16384, 256, 0, stream>>>(x, xbf);
  // routed weights: gate/up [1024][512] -> W1 interleaved rows; down [512][1024] -> Dt plain
  k_transpose_cvt<<<dim3(16, 32, 8), 256, 0, stream>>>(gw, W1, 512, 1,
                                                       (size_t)1024 * 512, (size_t)1 << 21);
  k_transpose_cvt<<<dim3(16, 32, 8), 256, 0, stream>>>(uw, W1, 512, 2,
                                                       (size_t)1024 * 512, (size_t)1 << 21);
  k_transpose_cvt<<<dim3(32, 16, 8), 256, 0, stream>>>(dw, Dt, 1024, 0,
                                                       (size_t)512 * 1024, (size_t)1 << 20);
  // shared weights appended (replicated per expert)
  k_copy_cvt<<<dim3(512, 1, 8), 256, 0, stream>>>(sgw, W1, 1024, 1, 0, (size_t)1 << 21);
  k_copy_cvt<<<dim3(512, 1, 8), 256, 0, stream>>>(suw, W1, 1024, 2, 0, (size_t)1 << 21);
  k_copy_cvt<<<dim3(512, 1, 8), 256, 0, stream>>>(sdw, Dt, 512, 0, 512, (size_t)1 << 20);
  // grouped GEMMs (256^2 tiles, 8-phase read-ahead pipeline)
  k_gu<<<dim3(8, 128, 8), 512, 0, stream>>>(xbf, W1, perm, ctrl, ctrl + 16, inter);
  k_down<<<dim3(4, 128, 8), 512, 0, stream>>>(inter, Dt, perm, ctrl, ctrl + 16, out);
}